// Round 13
// baseline (911.203 us; speedup 1.0000x reference)
//
#include <hip/hip_runtime.h>
#include <stdint.h>

#define T_STEPS 1024
#define BATCH   512
#define INF     64
#define HID     128
#define OUTF    2

// d_out[0..1023] = z_sum [512][2], d_out[1024] = spikerate.
__global__ void zero_kernel(unsigned int* __restrict__ counter)
{
    *counter = 0u;
}

#define FOR16(M) M(0)M(1)M(2)M(3)M(4)M(5)M(6)M(7)M(8)M(9)M(10)M(11)M(12)M(13)M(14)M(15)
#define FOR32(M) FOR16(M) M(16)M(17)M(18)M(19)M(20)M(21)M(22)M(23)M(24)M(25)M(26)M(27)M(28)M(29)M(30)M(31)

#define BARRIER() asm volatile("s_waitcnt lgkmcnt(0)\n\ts_barrier" ::: "memory")
// Pin a float4 into VGPRs: value becomes asm-defined -> no remat/demotion.
#define PIN4(v) asm volatile("" : "+v"(v.x), "+v"(v.y), "+v"(v.z), "+v"(v.w))

// grid 512 x 256 threads; block = ONE batch row b = blockIdx.x. 66.5KB LDS -> 2 blocks/CU.
// launch_bounds(256,2): min 2 waves/EU -> VGPR cap 256 (weights register-resident).
// Roles (wave-aligned):
//   tid   0..127 : stage2 waves  — pre(i+1) = inp(i+1)@cWi.T (32 float4 PINNED in VGPRs;
//                  inp reads are same-address broadcasts = conflict-free)
//   tid 128..191 : stage1 wave   — inp(i+2) = x(i+2)@W_in.T, 2 outputs/lane (32 float4 PINNED)
//   tid 192..255 : rec wave      — 2 neurons/lane; masks in-register via 2 ballots;
//                  batched b64 scan of Wrec_T; LIF; no LDS writes in loop.
// Bit-exact semantics (verified absmax==0.0 rounds 8-12):
//   - v,i state + elementwise: float64, np op order, no contraction
//   - inp/pre: f32 seq-k single-accumulator FMA chains (class-A)
//   - rec: f64 sum of f32 weights — exact in any order
__global__ __launch_bounds__(256, 2)
void snn_seq(const float* __restrict__ x,        // [T][B][64]
             const float* __restrict__ W_in,     // [128][64]
             const float* __restrict__ cWi,      // [128][128]
             const float* __restrict__ Wrec,     // [128][128]
             const float* __restrict__ W_out,    // [2][128]
             const float* __restrict__ b_out,    // [2]
             const float* __restrict__ v_th,     // [128]
             const float* __restrict__ v_leak1,  // [1]
             const float* __restrict__ v_reset,  // [128]
             const float* __restrict__ tau_mem,  // [128]
             const float* __restrict__ tau_syn,  // [128]
             float* __restrict__ out,            // [512][2] + [1]
             unsigned int* __restrict__ counter)
{
    #pragma clang fp contract(off)

    extern __shared__ char smem[];
    float* Wrec_T  = (float*)smem;                 // [128][128]: Wrec_T[j][h] = Wrec[h][j]
    float* x_lds   = Wrec_T + HID * HID;           // [2 buf][64]
    float* inp_lds = x_lds + 2 * INF;              // [2 buf][128]
    float* pre_lds = inp_lds + 2 * HID;            // [2 buf][128]

    const int tid = threadIdx.x;
    const int b   = blockIdx.x;

    // ---- stage Wrec transposed (all threads); stage1 wave stages x(0),x(1)
    for (int idx = tid; idx < HID * HID; idx += 256)
        Wrec_T[idx] = Wrec[(idx & (HID - 1)) * HID + (idx >> 7)];
    if (tid >= 128 && tid < 192) {
        int l = tid - 128;
        x_lds[0 * INF + l] = x[(size_t)(0 * BATCH + b) * INF + l];
        x_lds[1 * INF + l] = x[(size_t)(1 * BATCH + b) * INF + l];
    }
    __syncthreads();

    if (tid < 128) {
        // ================= STAGE2 role: pre = inp @ cWi.T =================
        const int h = tid;
        const float4* cwr = (const float4*)(cWi + h * HID);
        #define DECL_C(q) float4 c##q = cwr[q];
        FOR32(DECL_C)
        #undef DECL_C
        #define PIN_C(q) PIN4(c##q);
        FOR32(PIN_C)
        #undef PIN_C

        BARRIER();   // P1 (stage1 computes inp(0))

        // P2: pre(0) from inp_lds[0]
        {
            const float4* ir4 = (const float4*)(inp_lds + 0 * HID);
            float p = 0.f;
            #define S2(q) { float4 i4 = ir4[q]; \
                p = fmaf(i4.x, c##q.x, p); p = fmaf(i4.y, c##q.y, p); \
                p = fmaf(i4.z, c##q.z, p); p = fmaf(i4.w, c##q.w, p); }
            FOR32(S2)
            #undef S2
            pre_lds[0 * HID + h] = p;
            BARRIER();

            for (int i = 0; i < T_STEPS; ++i) {
                const int nbuf = (i & 1) ^ 1;
                const float4* ir = (const float4*)(inp_lds + nbuf * HID); // inp(i+1)
                float pp = 0.f;
                #define S2(q) { float4 i4 = ir[q]; \
                    pp = fmaf(i4.x, c##q.x, pp); pp = fmaf(i4.y, c##q.y, pp); \
                    pp = fmaf(i4.z, c##q.z, pp); pp = fmaf(i4.w, c##q.w, pp); }
                FOR32(S2)
                #undef S2
                pre_lds[nbuf * HID + h] = pp;                             // pre(i+1)
                BARRIER();
            }
        }
    } else if (tid < 192) {
        // ================= STAGE1 role: inp = x @ W_in.T (2 outputs/lane) =================
        const int l = tid - 128;
        const float4* wra = (const float4*)(W_in + l * INF);
        const float4* wrb = (const float4*)(W_in + (l + 64) * INF);
        #define DECL_AB(q) float4 a##q = wra[q]; float4 b##q = wrb[q];
        FOR16(DECL_AB)
        #undef DECL_AB
        #define PIN_AB(q) PIN4(a##q); PIN4(b##q);
        FOR16(PIN_AB)
        #undef PIN_AB

        #define S1(q) { float4 x4 = xr4[q]; \
            sa = fmaf(x4.x, a##q.x, sa); sa = fmaf(x4.y, a##q.y, sa); \
            sa = fmaf(x4.z, a##q.z, sa); sa = fmaf(x4.w, a##q.w, sa); \
            sb = fmaf(x4.x, b##q.x, sb); sb = fmaf(x4.y, b##q.y, sb); \
            sb = fmaf(x4.z, b##q.z, sb); sb = fmaf(x4.w, b##q.w, sb); }

        // P1: inp(0) from xbuf0
        {
            const float4* xr4 = (const float4*)(x_lds + 0 * INF);
            float sa = 0.f, sb = 0.f;
            FOR16(S1)
            inp_lds[0 * HID + l] = sa;
            inp_lds[0 * HID + 64 + l] = sb;
        }
        BARRIER();

        // P2: inp(1) from xbuf1; restage xbuf0 <- x(2); issue x(3)
        float xnext;
        {
            const float4* xr4 = (const float4*)(x_lds + 1 * INF);
            float sa = 0.f, sb = 0.f;
            FOR16(S1)
            inp_lds[1 * HID + l] = sa;
            inp_lds[1 * HID + 64 + l] = sb;
            x_lds[0 * INF + l] = x[(size_t)(2 * BATCH + b) * INF + l];
            xnext = x[(size_t)(3 * BATCH + b) * INF + l];
        }
        BARRIER();

        for (int i = 0; i < T_STEPS; ++i) {
            const int buf  = i & 1;
            const int nbuf = buf ^ 1;
            // x handoff: ds_write x(i+3); issue load x(i+4) (in flight across barrier)
            x_lds[nbuf * INF + l] = xnext;
            int tn = (i + 4 < T_STEPS) ? i + 4 : T_STEPS - 1;
            xnext = x[((size_t)tn * BATCH + b) * INF + l];
            // inp(i+2) from xbuf[buf] = x(i+2)
            const float4* xr4 = (const float4*)(x_lds + buf * INF);
            float sa = 0.f, sb = 0.f;
            FOR16(S1)
            inp_lds[buf * HID + l] = sa;
            inp_lds[buf * HID + 64 + l] = sb;
            BARRIER();
        }
        #undef S1
    } else {
        // ================= REC role: rec scan + LIF, 2 neurons/lane =================
        const int l  = tid - 192;
        const int h0 = 2 * l, h1 = 2 * l + 1;

        const double vth0  = (double)v_th[h0],    vth1  = (double)v_th[h1];
        const double vleak = (double)v_leak1[0];
        const double vrs0  = (double)v_reset[h0], vrs1  = (double)v_reset[h1];
        const double dtm0  = 0.001 * (double)tau_mem[h0];
        const double dtm1  = 0.001 * (double)tau_mem[h1];
        const double dts0  = 0.001 * (double)tau_syn[h0];
        const double dts1  = 0.001 * (double)tau_syn[h1];

        double v0 = 0.0, v1 = 0.0, c0 = 0.0, c1 = 0.0;
        int cnt0 = 0, cnt1 = 0;
        unsigned long long me = 0ull, mo = 0ull;   // masks z(i-1): even / odd neurons

        BARRIER();   // P1
        BARRIER();   // P2

        for (int i = 0; i < T_STEPS; ++i) {
            const int buf = i & 1;
            // pre(i) pair (adjacent f32) — issue early
            float2 pp = *(const float2*)(pre_lds + buf * HID + h0);

            // scan: rec = sum over spiking j of Wrec_T[j][h]  (f64-exact, any order)
            double s00 = 0.0, s01 = 0.0, s10 = 0.0, s11 = 0.0;
            {
                unsigned long long A = me, Bm = mo;
                while (A | Bm) {
                    float2 w0 = make_float2(0.f, 0.f), w1 = w0, w2 = w0, w3 = w0,
                           w4 = w0, w5 = w0, w6 = w0, w7 = w0;
                    if (A)  { int j = __builtin_ctzll(A);  A  &= A - 1;  w0 = *(const float2*)(Wrec_T + (2 * j) * HID + h0); }
                    if (A)  { int j = __builtin_ctzll(A);  A  &= A - 1;  w1 = *(const float2*)(Wrec_T + (2 * j) * HID + h0); }
                    if (A)  { int j = __builtin_ctzll(A);  A  &= A - 1;  w2 = *(const float2*)(Wrec_T + (2 * j) * HID + h0); }
                    if (A)  { int j = __builtin_ctzll(A);  A  &= A - 1;  w3 = *(const float2*)(Wrec_T + (2 * j) * HID + h0); }
                    if (Bm) { int j = __builtin_ctzll(Bm); Bm &= Bm - 1; w4 = *(const float2*)(Wrec_T + (2 * j + 1) * HID + h0); }
                    if (Bm) { int j = __builtin_ctzll(Bm); Bm &= Bm - 1; w5 = *(const float2*)(Wrec_T + (2 * j + 1) * HID + h0); }
                    if (Bm) { int j = __builtin_ctzll(Bm); Bm &= Bm - 1; w6 = *(const float2*)(Wrec_T + (2 * j + 1) * HID + h0); }
                    if (Bm) { int j = __builtin_ctzll(Bm); Bm &= Bm - 1; w7 = *(const float2*)(Wrec_T + (2 * j + 1) * HID + h0); }
                    s00 += (double)w0.x; s10 += (double)w0.y;
                    s01 += (double)w1.x; s11 += (double)w1.y;
                    s00 += (double)w2.x; s10 += (double)w2.y;
                    s01 += (double)w3.x; s11 += (double)w3.y;
                    s00 += (double)w4.x; s10 += (double)w4.y;
                    s01 += (double)w5.x; s11 += (double)w5.y;
                    s00 += (double)w6.x; s10 += (double)w6.y;
                    s01 += (double)w7.x; s11 += (double)w7.y;
                }
            }
            double rec0 = s00 + s01;
            double rec1 = s10 + s11;

            // LIF (float64, np op order, no contraction)
            double vd0 = v0 + dtm0 * ((vleak - v0) + c0);
            double id0 = c0 - dts0 * c0;
            bool   z0  = (vd0 - vth0) > 0.0;
            v0 = z0 ? vrs0 : vd0;
            c0 = (id0 + (double)pp.x) + rec0;
            cnt0 += z0 ? 1 : 0;

            double vd1 = v1 + dtm1 * ((vleak - v1) + c1);
            double id1 = c1 - dts1 * c1;
            bool   z1  = (vd1 - vth1) > 0.0;
            v1 = z1 ? vrs1 : vd1;
            c1 = (id1 + (double)pp.y) + rec1;
            cnt1 += z1 ? 1 : 0;

            me = __ballot(z0);   // masks for step i+1, stay in-wave
            mo = __ballot(z1);
            BARRIER();
        }

        // park counts for epilogue
        pre_lds[h0] = (float)cnt0;   // counts <= 1024: exact in f32
        pre_lds[h1] = (float)cnt1;
    }

    __syncthreads();

    // ---- epilogue: z_sum[b] = (sum_t z)@W_out.T + T*b_out ; global spike count
    const float* cnt_lds = pre_lds;
    if (tid < OUTF) {
        double sAcc = 0.0;
        for (int hh = 0; hh < HID; ++hh)
            sAcc += (double)cnt_lds[hh] * (double)W_out[tid * HID + hh];
        out[(size_t)b * OUTF + tid] = (float)(sAcc + 1024.0 * (double)b_out[tid]);
    }
    if (tid == 0) {
        unsigned int tot = 0;
        for (int k2 = 0; k2 < HID; ++k2) tot += (unsigned int)cnt_lds[k2];
        atomicAdd(counter, tot);
    }
}

__global__ void finalize_kernel(float* __restrict__ out)
{
    unsigned int c = ((const unsigned int*)out)[BATCH * OUTF];
    out[BATCH * OUTF] = (float)c * 0x1p-26f;   // / (1024*512*128), exact pow2
}

extern "C" void kernel_launch(void* const* d_in, const int* in_sizes, int n_in,
                              void* d_out, int out_size, void* d_ws, size_t ws_size,
                              hipStream_t stream) {
    (void)in_sizes; (void)n_in; (void)d_ws; (void)ws_size; (void)out_size;

    const float* x       = (const float*)d_in[0];
    const float* W_in    = (const float*)d_in[1];
    const float* cWi     = (const float*)d_in[2];
    const float* cWr     = (const float*)d_in[3];
    const float* W_out   = (const float*)d_in[4];
    const float* b_out   = (const float*)d_in[5];
    // d_in[6] = alpha (unused in forward)
    const float* v_th    = (const float*)d_in[7];
    const float* v_leak  = (const float*)d_in[8];
    const float* v_reset = (const float*)d_in[9];
    const float* tau_mem = (const float*)d_in[10];
    const float* tau_syn = (const float*)d_in[11];
    float* out = (float*)d_out;
    unsigned int* counter = (unsigned int*)out + BATCH * OUTF;

    zero_kernel<<<1, 1, 0, stream>>>(counter);

    const size_t lds_bytes =
        (size_t)(HID * HID + 2 * INF + 2 * HID + 2 * HID) * sizeof(float);
    snn_seq<<<dim3(512), dim3(256), lds_bytes, stream>>>(
        x, W_in, cWi, cWr, W_out, b_out, v_th, v_leak, v_reset,
        tau_mem, tau_syn, out, counter);

    finalize_kernel<<<1, 1, 0, stream>>>(out);
}

// Round 14
// 617.256 us; speedup vs baseline: 1.4762x; 1.4762x over previous
//
#include <hip/hip_runtime.h>
#include <stdint.h>

#define T_STEPS 1024
#define BATCH   512
#define INF     64
#define HID     128
#define OUTF    2

// d_out[0..1023] = z_sum [512][2], d_out[1024] = spikerate.
__global__ void zero_kernel(unsigned int* __restrict__ counter)
{
    *counter = 0u;
}

#define FOR16(M) M(0)M(1)M(2)M(3)M(4)M(5)M(6)M(7)M(8)M(9)M(10)M(11)M(12)M(13)M(14)M(15)
#define BARRIER() asm volatile("s_waitcnt lgkmcnt(0)\n\ts_barrier" ::: "memory")

// grid 512 x 512 threads; block = ONE batch row b. 69KB LDS -> 2 blocks/CU.
// launch_bounds(512,4): 4 waves/EU (the compiler's natural budget) -> 128 VGPR cap;
// every role needs <= ~100 VGPRs (max 16 float4 weights) -> weights stay resident.
// Roles (wave-aligned), pipeline at step i:
//   tid   0..127 (W2a): q(i+2)   = f32 chain k=0..63   of inp(i+2)      -> q_lds
//   tid 128..255 (W2b): pre(i+1) = f32 chain k=64..127 CONTINUING q(i+1)-> pre_lds
//   tid 256..383 (W1) : inp(i+3) = x(i+3) @ W_in.T (64-chain, 1 out/lane)-> inp_lds
//   tid 384..447 (R)  : step i: rec scan (in-reg masks) + LIF + ballots
//   tid 448..511 (X)  : x prefetch: ds_write x(i+5/i+6), issue load x(i+7/i+8)
// Buffers: inp[4], x[4], q[2], pre[2]; every handoff crosses >=1 barrier.
// Bit-exact semantics (verified absmax==0.0 rounds 8-13):
//   - v,i state + elementwise: float64, np op order, no contraction
//   - inp/pre: f32 seq-k single-accumulator FMA chains (K-split passes the exact
//     f32 partial through LDS -> identical op sequence)
//   - rec: f64 sum of f32 weights — exact in any order
__global__ __launch_bounds__(512, 4)
void snn_seq(const float* __restrict__ x,        // [T][B][64]
             const float* __restrict__ W_in,     // [128][64]
             const float* __restrict__ cWi,      // [128][128]
             const float* __restrict__ Wrec,     // [128][128]
             const float* __restrict__ W_out,    // [2][128]
             const float* __restrict__ b_out,    // [2]
             const float* __restrict__ v_th,     // [128]
             const float* __restrict__ v_leak1,  // [1]
             const float* __restrict__ v_reset,  // [128]
             const float* __restrict__ tau_mem,  // [128]
             const float* __restrict__ tau_syn,  // [128]
             float* __restrict__ out,            // [512][2] + [1]
             unsigned int* __restrict__ counter)
{
    #pragma clang fp contract(off)

    extern __shared__ char smem[];
    float* Wrec_T  = (float*)smem;                 // [128][128]: Wrec_T[j][h] = Wrec[h][j]
    float* inp_lds = Wrec_T + HID * HID;           // [4 slot][128]
    float* x_lds   = inp_lds + 4 * HID;            // [4 slot][64]
    float* q_lds   = x_lds + 4 * INF;              // [2 slot][128]
    float* pre_lds = q_lds + 2 * HID;              // [2 slot][128]

    const int tid = threadIdx.x;
    const int b   = blockIdx.x;

    // ---- stage Wrec transposed (all 512 threads)
    for (int idx = tid; idx < HID * HID; idx += 512)
        Wrec_T[idx] = Wrec[(idx & (HID - 1)) * HID + (idx >> 7)];

    if (tid < 128) {
        // ============ W2a: q = chain(inp[0..63]) with cWi row first half ============
        const int h = tid;
        const float4* cwr = (const float4*)(cWi + h * HID);
        #define DECL_C(q) float4 c##q = cwr[q];
        FOR16(DECL_C)
        #undef DECL_C

        #define S2A(q) { float4 i4 = ir4[q]; \
            acc = fmaf(i4.x, c##q.x, acc); acc = fmaf(i4.y, c##q.y, acc); \
            acc = fmaf(i4.z, c##q.z, acc); acc = fmaf(i4.w, c##q.w, acc); }

        __syncthreads();                       // B0
        BARRIER();                             // B1 (W1 computed inp(0))
        {   // P2: q(0)
            const float4* ir4 = (const float4*)(inp_lds + 0 * HID);
            float acc = 0.f; FOR16(S2A)
            q_lds[0 * HID + h] = acc;
        }
        BARRIER();                             // B2
        {   // P3: q(1)
            const float4* ir4 = (const float4*)(inp_lds + 1 * HID);
            float acc = 0.f; FOR16(S2A)
            q_lds[1 * HID + h] = acc;
        }
        BARRIER();                             // B3
        for (int i = 0; i < T_STEPS; i += 2) {
            {   // even: q(i+2), slot (i+2)&3, qslot (i+2)&1 = 0
                const float4* ir4 = (const float4*)(inp_lds + ((i + 2) & 3) * HID);
                float acc = 0.f; FOR16(S2A)
                q_lds[0 * HID + h] = acc;
            }
            BARRIER();
            {   // odd: q(i+3), slot (i+3)&3, qslot 1
                const float4* ir4 = (const float4*)(inp_lds + ((i + 3) & 3) * HID);
                float acc = 0.f; FOR16(S2A)
                q_lds[1 * HID + h] = acc;
            }
            BARRIER();
        }
        #undef S2A
    } else if (tid < 256) {
        // ============ W2b: pre = chain(q, inp[64..127]) with cWi row second half ============
        const int h = tid - 128;
        const float4* cwr = (const float4*)(cWi + h * HID) + 16;
        #define DECL_D(q) float4 d##q = cwr[q];
        FOR16(DECL_D)
        #undef DECL_D

        #define S2B(q) { float4 i4 = ir4[q]; \
            acc = fmaf(i4.x, d##q.x, acc); acc = fmaf(i4.y, d##q.y, acc); \
            acc = fmaf(i4.z, d##q.z, acc); acc = fmaf(i4.w, d##q.w, acc); }

        __syncthreads();                       // B0
        BARRIER();                             // B1
        BARRIER();                             // B2
        {   // P3: pre(0) from q(0), inp(0)[64..127]
            const float4* ir4 = (const float4*)(inp_lds + 0 * HID) + 16;
            float acc = q_lds[0 * HID + h];
            FOR16(S2B)
            pre_lds[0 * HID + h] = acc;
        }
        BARRIER();                             // B3
        for (int i = 0; i < T_STEPS; i += 2) {
            {   // even: pre(i+1), inp slot (i+1)&3, q/pre slot 1
                const float4* ir4 = (const float4*)(inp_lds + ((i + 1) & 3) * HID) + 16;
                float acc = q_lds[1 * HID + h];
                FOR16(S2B)
                pre_lds[1 * HID + h] = acc;
            }
            BARRIER();
            {   // odd: pre(i+2), inp slot (i+2)&3, q/pre slot 0
                const float4* ir4 = (const float4*)(inp_lds + ((i + 2) & 3) * HID) + 16;
                float acc = q_lds[0 * HID + h];
                FOR16(S2B)
                pre_lds[0 * HID + h] = acc;
            }
            BARRIER();
        }
        #undef S2B
    } else if (tid < 384) {
        // ============ W1: inp = x @ W_in.T, one output/lane ============
        const int l = tid - 256;
        const float4* wra = (const float4*)(W_in + l * INF);
        #define DECL_A(q) float4 a##q = wra[q];
        FOR16(DECL_A)
        #undef DECL_A

        #define S1(q) { float4 x4 = xr4[q]; \
            acc = fmaf(x4.x, a##q.x, acc); acc = fmaf(x4.y, a##q.y, acc); \
            acc = fmaf(x4.z, a##q.z, acc); acc = fmaf(x4.w, a##q.w, acc); }

        __syncthreads();                       // B0 (x(0..3) staged by X)
        {   // P1: inp(0)
            const float4* xr4 = (const float4*)(x_lds + 0 * INF);
            float acc = 0.f; FOR16(S1)
            inp_lds[0 * HID + l] = acc;
        }
        BARRIER();                             // B1
        {   // P2: inp(1)
            const float4* xr4 = (const float4*)(x_lds + 1 * INF);
            float acc = 0.f; FOR16(S1)
            inp_lds[1 * HID + l] = acc;
        }
        BARRIER();                             // B2
        {   // P3: inp(2)
            const float4* xr4 = (const float4*)(x_lds + 2 * INF);
            float acc = 0.f; FOR16(S1)
            inp_lds[2 * HID + l] = acc;
        }
        BARRIER();                             // B3
        for (int i = 0; i < T_STEPS; i += 2) {
            {   // even: inp(i+3), x/inp slot (i+3)&3
                const int s = (i + 3) & 3;
                const float4* xr4 = (const float4*)(x_lds + s * INF);
                float acc = 0.f; FOR16(S1)
                inp_lds[s * HID + l] = acc;
            }
            BARRIER();
            {   // odd: inp(i+4), slot (i+4)&3
                const int s = (i + 4) & 3;
                const float4* xr4 = (const float4*)(x_lds + s * INF);
                float acc = 0.f; FOR16(S1)
                inp_lds[s * HID + l] = acc;
            }
            BARRIER();
        }
        #undef S1
    } else if (tid < 448) {
        // ============ R: rec scan + LIF, 2 neurons/lane ============
        const int l  = tid - 384;
        const int h0 = 2 * l, h1 = 2 * l + 1;

        const double vth0  = (double)v_th[h0],    vth1  = (double)v_th[h1];
        const double vleak = (double)v_leak1[0];
        const double vrs0  = (double)v_reset[h0], vrs1  = (double)v_reset[h1];
        const double dtm0  = 0.001 * (double)tau_mem[h0];
        const double dtm1  = 0.001 * (double)tau_mem[h1];
        const double dts0  = 0.001 * (double)tau_syn[h0];
        const double dts1  = 0.001 * (double)tau_syn[h1];

        double v0 = 0.0, v1 = 0.0, c0 = 0.0, c1 = 0.0;
        int cnt0 = 0, cnt1 = 0;
        unsigned long long me = 0ull, mo = 0ull;   // z(i-1): even/odd neurons

        __syncthreads();                       // B0
        BARRIER(); BARRIER(); BARRIER();       // B1,B2,B3

        for (int i = 0; i < T_STEPS; ++i) {
            float2 pp = *(const float2*)(pre_lds + (i & 1) * HID + h0);  // pre(i)

            double s00 = 0.0, s01 = 0.0, s10 = 0.0, s11 = 0.0;
            {
                unsigned long long A = me, Bm = mo;
                while (A | Bm) {
                    float2 w0 = make_float2(0.f, 0.f), w1 = w0, w2 = w0, w3 = w0,
                           w4 = w0, w5 = w0, w6 = w0, w7 = w0;
                    if (A)  { int j = __builtin_ctzll(A);  A  &= A - 1;  w0 = *(const float2*)(Wrec_T + (2 * j) * HID + h0); }
                    if (A)  { int j = __builtin_ctzll(A);  A  &= A - 1;  w1 = *(const float2*)(Wrec_T + (2 * j) * HID + h0); }
                    if (A)  { int j = __builtin_ctzll(A);  A  &= A - 1;  w2 = *(const float2*)(Wrec_T + (2 * j) * HID + h0); }
                    if (A)  { int j = __builtin_ctzll(A);  A  &= A - 1;  w3 = *(const float2*)(Wrec_T + (2 * j) * HID + h0); }
                    if (Bm) { int j = __builtin_ctzll(Bm); Bm &= Bm - 1; w4 = *(const float2*)(Wrec_T + (2 * j + 1) * HID + h0); }
                    if (Bm) { int j = __builtin_ctzll(Bm); Bm &= Bm - 1; w5 = *(const float2*)(Wrec_T + (2 * j + 1) * HID + h0); }
                    if (Bm) { int j = __builtin_ctzll(Bm); Bm &= Bm - 1; w6 = *(const float2*)(Wrec_T + (2 * j + 1) * HID + h0); }
                    if (Bm) { int j = __builtin_ctzll(Bm); Bm &= Bm - 1; w7 = *(const float2*)(Wrec_T + (2 * j + 1) * HID + h0); }
                    s00 += (double)w0.x; s10 += (double)w0.y;
                    s01 += (double)w1.x; s11 += (double)w1.y;
                    s00 += (double)w2.x; s10 += (double)w2.y;
                    s01 += (double)w3.x; s11 += (double)w3.y;
                    s00 += (double)w4.x; s10 += (double)w4.y;
                    s01 += (double)w5.x; s11 += (double)w5.y;
                    s00 += (double)w6.x; s10 += (double)w6.y;
                    s01 += (double)w7.x; s11 += (double)w7.y;
                }
            }
            double rec0 = s00 + s01;
            double rec1 = s10 + s11;

            double vd0 = v0 + dtm0 * ((vleak - v0) + c0);
            double id0 = c0 - dts0 * c0;
            bool   z0  = (vd0 - vth0) > 0.0;
            v0 = z0 ? vrs0 : vd0;
            c0 = (id0 + (double)pp.x) + rec0;
            cnt0 += z0 ? 1 : 0;

            double vd1 = v1 + dtm1 * ((vleak - v1) + c1);
            double id1 = c1 - dts1 * c1;
            bool   z1  = (vd1 - vth1) > 0.0;
            v1 = z1 ? vrs1 : vd1;
            c1 = (id1 + (double)pp.y) + rec1;
            cnt1 += z1 ? 1 : 0;

            me = __ballot(z0);
            mo = __ballot(z1);
            BARRIER();
        }

        pre_lds[h0] = (float)cnt0;   // park counts (counts <= 1024: exact)
        pre_lds[h1] = (float)cnt1;
    } else {
        // ============ X: x prefetch wave ============
        const int l = tid - 448;
        // stage x(0..3) -> slots 0..3; preload x(4),x(5),x(6)
        float t0 = x[(size_t)(0 * BATCH + b) * INF + l];
        float t1 = x[(size_t)(1 * BATCH + b) * INF + l];
        float t2 = x[(size_t)(2 * BATCH + b) * INF + l];
        float t3 = x[(size_t)(3 * BATCH + b) * INF + l];
        x_lds[0 * INF + l] = t0;
        x_lds[1 * INF + l] = t1;
        x_lds[2 * INF + l] = t2;
        x_lds[3 * INF + l] = t3;
        float rC = x[(size_t)(4 * BATCH + b) * INF + l];
        float rA = x[(size_t)(5 * BATCH + b) * INF + l];
        float rB = x[(size_t)(6 * BATCH + b) * INF + l];

        __syncthreads();                       // B0
        BARRIER();                             // B1
        BARRIER();                             // B2
        x_lds[0 * INF + l] = rC;               // P3: x(4) -> slot 0
        BARRIER();                             // B3
        for (int i = 0; i < T_STEPS; i += 2) {
            {   // even: write x(i+5), load x(i+7)
                x_lds[((i + 5) & 3) * INF + l] = rA;
                int tn = (i + 7 < T_STEPS) ? i + 7 : T_STEPS - 1;
                rA = x[((size_t)tn * BATCH + b) * INF + l];
            }
            BARRIER();
            {   // odd: write x(i+6), load x(i+8)
                x_lds[((i + 6) & 3) * INF + l] = rB;
                int tn = (i + 8 < T_STEPS) ? i + 8 : T_STEPS - 1;
                rB = x[((size_t)tn * BATCH + b) * INF + l];
            }
            BARRIER();
        }
    }

    __syncthreads();

    // ---- epilogue: z_sum[b] = (sum_t z)@W_out.T + T*b_out ; global spike count
    const float* cnt_lds = pre_lds;
    if (tid < OUTF) {
        double sAcc = 0.0;
        for (int hh = 0; hh < HID; ++hh)
            sAcc += (double)cnt_lds[hh] * (double)W_out[tid * HID + hh];
        out[(size_t)b * OUTF + tid] = (float)(sAcc + 1024.0 * (double)b_out[tid]);
    }
    if (tid == 0) {
        unsigned int tot = 0;
        for (int k2 = 0; k2 < HID; ++k2) tot += (unsigned int)cnt_lds[k2];
        atomicAdd(counter, tot);
    }
}

__global__ void finalize_kernel(float* __restrict__ out)
{
    unsigned int c = ((const unsigned int*)out)[BATCH * OUTF];
    out[BATCH * OUTF] = (float)c * 0x1p-26f;   // / (1024*512*128), exact pow2
}

extern "C" void kernel_launch(void* const* d_in, const int* in_sizes, int n_in,
                              void* d_out, int out_size, void* d_ws, size_t ws_size,
                              hipStream_t stream) {
    (void)in_sizes; (void)n_in; (void)d_ws; (void)ws_size; (void)out_size;

    const float* x       = (const float*)d_in[0];
    const float* W_in    = (const float*)d_in[1];
    const float* cWi     = (const float*)d_in[2];
    const float* cWr     = (const float*)d_in[3];
    const float* W_out   = (const float*)d_in[4];
    const float* b_out   = (const float*)d_in[5];
    // d_in[6] = alpha (unused in forward)
    const float* v_th    = (const float*)d_in[7];
    const float* v_leak  = (const float*)d_in[8];
    const float* v_reset = (const float*)d_in[9];
    const float* tau_mem = (const float*)d_in[10];
    const float* tau_syn = (const float*)d_in[11];
    float* out = (float*)d_out;
    unsigned int* counter = (unsigned int*)out + BATCH * OUTF;

    zero_kernel<<<1, 1, 0, stream>>>(counter);

    const size_t lds_bytes =
        (size_t)(HID * HID + 4 * HID + 4 * INF + 2 * HID + 2 * HID) * sizeof(float);
    snn_seq<<<dim3(512), dim3(512), lds_bytes, stream>>>(
        x, W_in, cWi, cWr, W_out, b_out, v_th, v_leak, v_reset,
        tau_mem, tau_syn, out, counter);

    finalize_kernel<<<1, 1, 0, stream>>>(out);
}